// Round 12
// baseline (429.611 us; speedup 1.0000x reference)
//
#include <hip/hip_runtime.h>

#define DM 1024
#define HEADS 16
#define DH 64
#define BB 4
#define LL 2048
#define MROWS (BB * LL) /* 8192 */

typedef __bf16 bf16x8 __attribute__((ext_vector_type(8)));
typedef float f32x4 __attribute__((ext_vector_type(4)));
typedef float f32x16 __attribute__((ext_vector_type(16)));

// HW round-to-nearest-even f32->bf16 via compiler (emits v_cvt_pk_bf16_f32)
__device__ __forceinline__ unsigned short f2bf(float f) {
  __bf16 h = (__bf16)f;
  return __builtin_bit_cast(unsigned short, h);
}
__device__ __forceinline__ unsigned int pack2(float a, float b) {
  return (unsigned int)f2bf(a) | ((unsigned int)f2bf(b) << 16);
}

// async global->LDS, 16B per lane; LDS dest is wave-uniform base + lane*16
__device__ __forceinline__ void gload16(const unsigned short* g, unsigned short* l) {
  __builtin_amdgcn_global_load_lds(
      (const __attribute__((address_space(1))) unsigned int*)(const void*)g,
      (__attribute__((address_space(3))) unsigned int*)(void*)l, 16, 0, 0);
}

// ---------------------------------------------------------------------------
// Weight transpose + bf16 convert: WT[n][k] = bf16(W[k][n]), 1024x1024, z=4
// ---------------------------------------------------------------------------
__global__ __launch_bounds__(256) void transpose_w_kernel(
    const float* __restrict__ W0, const float* __restrict__ W1,
    const float* __restrict__ W2, const float* __restrict__ W3,
    unsigned short* __restrict__ T0, unsigned short* __restrict__ T1,
    unsigned short* __restrict__ T2, unsigned short* __restrict__ T3) {
  const float* Wt[4] = {W0, W1, W2, W3};
  unsigned short* Tt[4] = {T0, T1, T2, T3};
  const float* W = Wt[blockIdx.z];
  unsigned short* WT = Tt[blockIdx.z];
  __shared__ float tile[32][33];
  const int tx = threadIdx.x & 31;
  const int ty = threadIdx.x >> 5;
  const int x0 = blockIdx.x * 32;
  const int y0 = blockIdx.y * 32;
#pragma unroll
  for (int i = 0; i < 32; i += 8)
    tile[ty + i][tx] = W[(size_t)(y0 + ty + i) * DM + x0 + tx];
  __syncthreads();
#pragma unroll
  for (int i = 0; i < 32; i += 8)
    WT[(size_t)(x0 + ty + i) * DM + y0 + tx] = f2bf(tile[tx][ty + i]);
}

// ---------------------------------------------------------------------------
// fp32 -> bf16 convert, 8 elems/thread, vectorized (single and 3-src merged)
// ---------------------------------------------------------------------------
__global__ __launch_bounds__(256) void cvt_bf16_kernel(
    const float* __restrict__ x, unsigned short* __restrict__ y) {
  const size_t i = ((size_t)blockIdx.x * 256 + threadIdx.x) * 8;
  float4 a = *(const float4*)(x + i);
  float4 b = *(const float4*)(x + i + 4);
  uint4 p = {pack2(a.x, a.y), pack2(a.z, a.w), pack2(b.x, b.y), pack2(b.z, b.w)};
  *(uint4*)(y + i) = p;
}

__global__ __launch_bounds__(256) void cvt3_bf16_kernel(
    const float* __restrict__ q, const float* __restrict__ k,
    const float* __restrict__ v, unsigned short* __restrict__ Xq,
    unsigned short* __restrict__ Xk, unsigned short* __restrict__ Xv) {
  const int z = blockIdx.y;
  const float* x = (z == 0) ? q : (z == 1) ? k : v;
  unsigned short* y = (z == 0) ? Xq : (z == 1) ? Xk : Xv;
  const size_t i = ((size_t)blockIdx.x * 256 + threadIdx.x) * 8;
  float4 a = *(const float4*)(x + i);
  float4 b = *(const float4*)(x + i + 4);
  uint4 p = {pack2(a.x, a.y), pack2(a.z, a.w), pack2(b.x, b.y), pack2(b.z, b.w)};
  *(uint4*)(y + i) = p;
}

// ---------------------------------------------------------------------------
// GEMM body (m97 structure, BK=32 -- reverted from BK=64 per m132 trap:
// 64KB LDS halves occupancy and adds 16-way frag-read conflicts).
// 128x128 tile, 256 thr (4 waves, 4x4 16x16x32 frags).
// Staging via global_load_lds width-16 into LINEAR LDS [128][32] (16 KB).
// OUTMODE 0: bf16 out scaled, head layout [B,H,L,DH].
// OUTMODE 1: fp32 row-major.
// OUTMODE 2: bf16 out, TRANSPOSED head layout [B,H,DH,L]  (for V)
// Bijective XCD swizzle over the (x,y) grid (nwg % 8 == 0).
// ---------------------------------------------------------------------------
template <int OUTMODE>
__device__ __forceinline__ void gemm_body32(
    const unsigned short* __restrict__ A, const unsigned short* __restrict__ BT,
    const float* __restrict__ bias, void* __restrict__ Cptr, float scale) {
  constexpr int K = DM, N = DM;
  __shared__ unsigned short As[128 * 32];
  __shared__ unsigned short Bs[128 * 32];
  const int t = threadIdx.x;
  const int lane = t & 63;
  const int w = t >> 6;
  const int wr = w >> 1, wc = w & 1;
  const int fr = lane & 15, kg = lane >> 4;

  // XCD-aware swizzle: consecutive swz within an XCD share A row-panels
  const int flat = blockIdx.y * gridDim.x + blockIdx.x;
  const int cpx = (gridDim.x * gridDim.y) >> 3;  // nwg/8, nwg%8==0
  const int swz = (flat & 7) * cpx + (flat >> 3);
  const int m0 = (swz / gridDim.x) * 128;
  const int n0 = (swz % gridDim.x) * 128;

  // staging: lane covers row (lane>>2), col-chunk (lane&3)*8 of a [64][32] half
  const int grow = lane >> 2, gcol8 = (lane & 3) * 8;

  f32x4 acc[4][4] = {};

  for (int kt = 0; kt < K / 32; ++kt) {
    const int k0 = kt * 32;
#pragma unroll
    for (int i = 0; i < 2; i++) {
      gload16(A + (size_t)(m0 + i * 64 + w * 16 + grow) * K + k0 + gcol8,
              &As[(i * 256 + w * 64 + lane) * 8]);
      gload16(BT + (size_t)(n0 + i * 64 + w * 16 + grow) * K + k0 + gcol8,
              &Bs[(i * 256 + w * 64 + lane) * 8]);
    }
    __syncthreads();  // drains vmcnt -> LDS tiles complete

    bf16x8 af[4], bfr[4];
#pragma unroll
    for (int i = 0; i < 4; i++)
      af[i] = *(const bf16x8*)&As[(wr * 64 + i * 16 + fr) * 32 + kg * 8];
#pragma unroll
    for (int i = 0; i < 4; i++)
      bfr[i] = *(const bf16x8*)&Bs[(wc * 64 + i * 16 + fr) * 32 + kg * 8];
#pragma unroll
    for (int i = 0; i < 4; i++)
#pragma unroll
      for (int j = 0; j < 4; j++)
        acc[i][j] = __builtin_amdgcn_mfma_f32_16x16x32_bf16(af[i], bfr[j], acc[i][j], 0, 0, 0);
    __syncthreads();
  }

#pragma unroll
  for (int j = 0; j < 4; j++) {
    const int gcol = n0 + wc * 64 + j * 16 + fr;
    const float bv = bias[gcol];
    const int h = gcol >> 6, dh = gcol & 63;
#pragma unroll
    for (int i = 0; i < 4; i++) {
      const int grow0 = m0 + wr * 64 + i * 16 + kg * 4;
      if (OUTMODE == 2) {
        const int b = grow0 >> 11, l = grow0 & 2047;
        uint2 pk;
        pk.x = pack2(acc[i][j][0] + bv, acc[i][j][1] + bv);
        pk.y = pack2(acc[i][j][2] + bv, acc[i][j][3] + bv);
        *(uint2*)((unsigned short*)Cptr +
                  ((size_t)((b * HEADS + h) * DH + dh)) * LL + l) = pk;
      } else {
#pragma unroll
        for (int r = 0; r < 4; r++) {
          const int grow2 = grow0 + r;
          if (OUTMODE == 0) {
            const float val = (acc[i][j][r] + bv) * scale;
            const int b = grow2 >> 11, l = grow2 & 2047;
            ((unsigned short*)Cptr)[(((size_t)(b * HEADS + h) * LL + l) << 6) + dh] = f2bf(val);
          } else {
            ((float*)Cptr)[(size_t)grow2 * N + gcol] = acc[i][j][r] + bv;
          }
        }
      }
    }
  }
}

// scale = 0.125 * log2(e) folded into Q so attention softmax can use exp2
#define QSCALE 0.18033688011112042f

// QKV projection: z = blockIdx.z + zoff selects {Q,K,V}.
__global__ __launch_bounds__(256) void qkv_gemm_kernel(
    const unsigned short* __restrict__ A0, size_t strideA,
    const unsigned short* __restrict__ WT0,
    const float* __restrict__ bq, const float* __restrict__ bk,
    const float* __restrict__ bv, unsigned short* __restrict__ O0, int zoff) {
  const int z = (int)blockIdx.z + zoff;
  const unsigned short* A = A0 + (size_t)z * strideA;
  const unsigned short* BT = WT0 + (size_t)z * DM * DM;
  const float* bias = (z == 0) ? bq : (z == 1) ? bk : bv;
  unsigned short* C = O0 + (size_t)z * MROWS * DM;
  if (z == 2)
    gemm_body32<2>(A, BT, bias, C, 1.0f);
  else
    gemm_body32<0>(A, BT, bias, C, (z == 0) ? QSCALE : 1.0f);
}

__global__ __launch_bounds__(256) void oproj_gemm_kernel(
    const unsigned short* __restrict__ Oc, const unsigned short* __restrict__ WoT,
    const float* __restrict__ bo, float* __restrict__ out) {
  gemm_body32<1>(Oc, WoT, bo, out, 1.0f);
}

// ---------------------------------------------------------------------------
// Causal flash attention, swapped-operand 32x32x16, NO LDS / NO BARRIERS.
// K/V fragments are read straight from global (L1/L2-resident: all 4 blocks
// of a CU share bh, each XCD's KV set = 4MB = one L2) -- Common-mistake #7:
// stage only when data doesn't cache-fit.  Waves past their diagonal simply
// finish (no barrier lockstep).
// Grid (16, 64) = 1024 blocks, one 128-row q-tile per block, 4 waves.
// CU-balanced zigzag mapping (dispatch CU ~ f&255, layer = f>>8):
//   qi = {sub, 7-sub, 8+sub, 15-sub}[layer] -> per-CU qi sum = 30 (uniform)
//   and each XCD owns 8 bh.
// Per wave: 32 q-rows; KV tiles of 64; Dh = 64.
// Defer-max rescale skip; softmax fully in-register.
// ---------------------------------------------------------------------------
__global__ __launch_bounds__(256, 8) void attn_kernel(
    const unsigned short* __restrict__ Qh, const unsigned short* __restrict__ Kh,
    const unsigned short* __restrict__ VhT, unsigned short* __restrict__ O) {
  const int t = threadIdx.x, lane = t & 63, w = t >> 6;  // w in 0..3
  const int lo5 = lane & 31, hi = lane >> 5;

  // CU-balanced, XCD-local decode
  const int f = (int)(blockIdx.y * gridDim.x + blockIdx.x);  // 0..1023
  const int l = f >> 8;        // co-resident layer 0..3
  const int c = f & 255;       // CU slot
  const int xcd = c & 7, j = c >> 3;
  const int bh = xcd * 8 + (j & 7);
  const int sub = j >> 3;      // 0..3
  const int qi = (l == 0) ? sub : (l == 1) ? 7 - sub : (l == 2) ? 8 + sub : 15 - sub;

  const size_t base = (size_t)bh * LL * DH;
  const unsigned short* Kb = Kh + base;   // [l][dh]
  const unsigned short* Vb = VhT + base;  // [dh][l]

  const int b = bh >> 4, h = bh & 15;
  const int q0 = qi * 128;
  const int qrow = q0 + w * 32 + lo5;  // this lane's q row

  // Q fragments: B-operand, col = q = lane&31, k = kc*16 + hi*8 + jj
  bf16x8 qf[4];
  {
    const unsigned short* Qb = Qh + base + (size_t)qrow * DH + hi * 8;
#pragma unroll
    for (int kc = 0; kc < 4; kc++) qf[kc] = *(const bf16x8*)(Qb + kc * 16);
  }

  float m_run = -INFINITY, l_run = 0.f;
  f32x16 oacc[2] = {};  // D[dh][q]

  const int my_last = (q0 + w * 32 + 31) >> 6;  // last KV tile this wave needs

  for (int jt = 0; jt <= my_last; ++jt) {
    const int kv0 = jt * 64;

    // S^T = K * Q^T : two 32x32 tiles along kv, K-dim = Dh = 64
    f32x16 s2[2] = {};
    __builtin_amdgcn_s_setprio(1);
#pragma unroll
    for (int tt = 0; tt < 2; tt++)
#pragma unroll
      for (int kc = 0; kc < 4; kc++) {
        bf16x8 kf = *(const bf16x8*)(Kb + (size_t)(kv0 + tt * 32 + lo5) * DH +
                                     kc * 16 + hi * 8);
        s2[tt] = __builtin_amdgcn_mfma_f32_32x32x16_bf16(kf, qf[kc], s2[tt], 0, 0, 0);
      }
    __builtin_amdgcn_s_setprio(0);

    // causal mask (wave-uniform condition; only diagonal-overlapping tiles)
    if (kv0 + 63 > q0 + w * 32) {
      const int thr = qrow - kv0 - 4 * hi;
#pragma unroll
      for (int tt = 0; tt < 2; tt++)
#pragma unroll
        for (int i = 0; i < 16; i++) {
          const int kvoff = tt * 32 + (i & 3) + 8 * (i >> 2);
          s2[tt][i] = (kvoff > thr) ? -1e30f : s2[tt][i];
        }
    }

    // row max: in-lane tree (max3-friendly) + cross-half shfl
    float mx;
    {
      float m8[8];
#pragma unroll
      for (int i = 0; i < 8; i++)
        m8[i] = fmaxf(fmaxf(s2[0][i], s2[0][i + 8]), fmaxf(s2[1][i], s2[1][i + 8]));
      const float a3 = fmaxf(fmaxf(m8[0], m8[1]), m8[2]);
      const float b3 = fmaxf(fmaxf(m8[3], m8[4]), m8[5]);
      const float c3 = fmaxf(m8[6], m8[7]);
      mx = fmaxf(fmaxf(a3, b3), c3);
    }
    mx = fmaxf(mx, __shfl_xor(mx, 32));

    // defer-max: only rescale when some row's max grew by >8 (2^8 P-bound)
    if (__any(mx > m_run + 8.0f)) {
      const float mnew = fmaxf(m_run, mx);
      const float corr = __builtin_amdgcn_exp2f(m_run - mnew);
      m_run = mnew;
      l_run *= corr;
#pragma unroll
      for (int od = 0; od < 2; od++)
#pragma unroll
        for (int i = 0; i < 16; i++) oacc[od][i] *= corr;
    }

    // p = exp2(s - m)   (logits pre-scaled by log2e at the Q projection)
#pragma unroll
    for (int tt = 0; tt < 2; tt++)
#pragma unroll
      for (int i = 0; i < 16; i++)
        s2[tt][i] = __builtin_amdgcn_exp2f(s2[tt][i] - m_run);

    // row sum: in-lane tree + cross-half shfl
    float rs;
    {
      float a8[8];
#pragma unroll
      for (int i = 0; i < 8; i++)
        a8[i] = (s2[0][i] + s2[0][i + 8]) + (s2[1][i] + s2[1][i + 8]);
#pragma unroll
      for (int st = 4; st > 0; st >>= 1)
#pragma unroll
        for (int i = 0; i < st; i++) a8[i] += a8[i + st];
      rs = a8[0];
    }
    rs += __shfl_xor(rs, 32);
    l_run += rs;

    // build P B-operand fragments: pa[ks] holds kv = ks*16 + hi*8 + jj
    union U8 { uint4 u; bf16x8 v; } pa[4];
#pragma unroll
    for (int ks = 0; ks < 4; ks++) {
      const int tt = ks >> 1, b0 = (ks & 1) * 8;
      const unsigned int w0 = pack2(s2[tt][b0 + 0], s2[tt][b0 + 1]);
      const unsigned int w1 = pack2(s2[tt][b0 + 2], s2[tt][b0 + 3]);
      const unsigned int w2 = pack2(s2[tt][b0 + 4], s2[tt][b0 + 5]);
      const unsigned int w3 = pack2(s2[tt][b0 + 6], s2[tt][b0 + 7]);
      const unsigned int p0 = (unsigned int)__shfl_xor((int)w0, 32);
      const unsigned int p1 = (unsigned int)__shfl_xor((int)w1, 32);
      const unsigned int p2 = (unsigned int)__shfl_xor((int)w2, 32);
      const unsigned int p3 = (unsigned int)__shfl_xor((int)w3, 32);
      pa[ks].u = hi ? make_uint4(p2, p3, w2, w3) : make_uint4(w0, w1, p0, p1);
    }

    // O^T += VT * P : D[dh][q]
    __builtin_amdgcn_s_setprio(1);
#pragma unroll
    for (int od = 0; od < 2; od++)
#pragma unroll
      for (int ks = 0; ks < 4; ks++) {
        bf16x8 vf = *(const bf16x8*)(Vb + (size_t)(od * 32 + lo5) * LL +
                                     kv0 + ks * 16 + hi * 8);
        oacc[od] = __builtin_amdgcn_mfma_f32_32x32x16_bf16(vf, pa[ks].v, oacc[od], 0, 0, 0);
      }
    __builtin_amdgcn_s_setprio(0);
  }

  // epilogue: O[b][l][h*64+dh] bf16; lane's q = qrow, dh = crow+od*32
  const float linv = 1.f / l_run;
  unsigned short* Ob = O + ((size_t)(b * LL + qrow) * DM) + h * DH;
#pragma unroll
  for (int od = 0; od < 2; od++)
#pragma unroll
    for (int m = 0; m < 8; m++) {
      const int dh0 = od * 32 + ((2 * m) & 3) + 8 * ((2 * m) >> 2) + 4 * hi;
      const unsigned int pk =
          pack2(oacc[od][2 * m] * linv, oacc[od][2 * m + 1] * linv);
      *(unsigned int*)(Ob + dh0) = pk;
    }
}

// ---------------------------------------------------------------------------
extern "C" void kernel_launch(void* const* d_in, const int* in_sizes, int n_in,
                              void* d_out, int out_size, void* d_ws, size_t ws_size,
                              hipStream_t stream) {
  (void)in_sizes; (void)n_in; (void)out_size;
  const float* q  = (const float*)d_in[0];
  const float* k  = (const float*)d_in[1];
  const float* v  = (const float*)d_in[2];
  const float* Wq = (const float*)d_in[3];
  const float* bq = (const float*)d_in[4];
  const float* Wk = (const float*)d_in[5];
  const float* bk = (const float*)d_in[6];
  const float* Wv = (const float*)d_in[7];
  const float* bv = (const float*)d_in[8];
  const float* Wo = (const float*)d_in[9];
  const float* bo = (const float*)d_in[10];

  char* ws = (char*)d_ws;
  const size_t WSZ = (size_t)DM * DM * 2;     // 2 MB per transposed weight
  const size_t HSZ = (size_t)MROWS * DM * 2;  // 16 MB per bf16 activation
  unsigned short* WT0 = (unsigned short*)(ws);             // WqT,WkT,WvT,WoT contiguous
  unsigned short* WoT = (unsigned short*)(ws + 3 * WSZ);
  unsigned short* Qh  = (unsigned short*)(ws + 4 * WSZ);   // Qh,Kh,VhT contiguous
  unsigned short* Kh  = (unsigned short*)(ws + 4 * WSZ + HSZ);
  unsigned short* VhT = (unsigned short*)(ws + 4 * WSZ + 2 * HSZ);
  unsigned short* X   = (unsigned short*)(ws + 4 * WSZ + 3 * HSZ);  // scratch, later Oc
  unsigned short* Oc  = X;  // X's contents dead once V-GEMM finishes

  transpose_w_kernel<<<dim3(32, 32, 4), 256, 0, stream>>>(
      Wq, Wk, Wv, Wo,
      WT0, WT0 + DM * DM, WT0 + 2 * (size_t)DM * DM, WoT);

  const dim3 cgrid(MROWS * DM / (256 * 8));
  const dim3 ggrid(DM / 128, MROWS / 128);
  const size_t NEED = 4 * WSZ + 6 * HSZ;  // 3 extra X buffers

  if (ws_size >= NEED) {
    // merged path: Xq,Xk,Xv separate -> one cvt launch + one QKV-GEMM launch
    unsigned short* Xq = X;
    unsigned short* Xk = X + (size_t)MROWS * DM;
    unsigned short* Xv = X + 2 * (size_t)MROWS * DM;
    cvt3_bf16_kernel<<<dim3(MROWS * DM / (256 * 8), 3), 256, 0, stream>>>(
        q, k, v, Xq, Xk, Xv);
    qkv_gemm_kernel<<<dim3(DM / 128, MROWS / 128, 3), 256, 0, stream>>>(
        Xq, (size_t)MROWS * DM, WT0, bq, bk, bv, Qh, 0);
  } else {
    // serial path: shared 16MB scratch
    cvt_bf16_kernel<<<cgrid, 256, 0, stream>>>(q, X);
    qkv_gemm_kernel<<<ggrid, 256, 0, stream>>>(X, 0, WT0, bq, bk, bv, Qh, 0);
    cvt_bf16_kernel<<<cgrid, 256, 0, stream>>>(k, X);
    qkv_gemm_kernel<<<ggrid, 256, 0, stream>>>(X, 0, WT0, bq, bk, bv, Qh, 1);
    cvt_bf16_kernel<<<cgrid, 256, 0, stream>>>(v, X);
    qkv_gemm_kernel<<<ggrid, 256, 0, stream>>>(X, 0, WT0, bq, bk, bv, Qh, 2);
  }

  attn_kernel<<<dim3(16, BB * HEADS), 256, 0, stream>>>(Qh, Kh, VhT, Oc);

  oproj_gemm_kernel<<<ggrid, 256, 0, stream>>>(Oc, WoT, bo, (float*)d_out);
}

// Round 13
// 199.707 us; speedup vs baseline: 2.1512x; 2.1512x over previous
//
#include <hip/hip_runtime.h>

#define DM 1024
#define HEADS 16
#define DH 64
#define BB 4
#define LL 2048
#define MROWS (BB * LL) /* 8192 */

typedef __bf16 bf16x8 __attribute__((ext_vector_type(8)));
typedef float f32x4 __attribute__((ext_vector_type(4)));
typedef float f32x16 __attribute__((ext_vector_type(16)));

// HW round-to-nearest-even f32->bf16 via compiler (emits v_cvt_pk_bf16_f32)
__device__ __forceinline__ unsigned short f2bf(float f) {
  __bf16 h = (__bf16)f;
  return __builtin_bit_cast(unsigned short, h);
}
__device__ __forceinline__ unsigned int pack2(float a, float b) {
  return (unsigned int)f2bf(a) | ((unsigned int)f2bf(b) << 16);
}

// async global->LDS, 16B per lane; LDS dest is wave-uniform base + lane*16
__device__ __forceinline__ void gload16(const unsigned short* g, unsigned short* l) {
  __builtin_amdgcn_global_load_lds(
      (const __attribute__((address_space(1))) unsigned int*)(const void*)g,
      (__attribute__((address_space(3))) unsigned int*)(void*)l, 16, 0, 0);
}

// ---------------------------------------------------------------------------
// Weight transpose + bf16 convert: WT[n][k] = bf16(W[k][n]), 1024x1024, z=4
// ---------------------------------------------------------------------------
__global__ __launch_bounds__(256) void transpose_w_kernel(
    const float* __restrict__ W0, const float* __restrict__ W1,
    const float* __restrict__ W2, const float* __restrict__ W3,
    unsigned short* __restrict__ T0, unsigned short* __restrict__ T1,
    unsigned short* __restrict__ T2, unsigned short* __restrict__ T3) {
  const float* Wt[4] = {W0, W1, W2, W3};
  unsigned short* Tt[4] = {T0, T1, T2, T3};
  const float* W = Wt[blockIdx.z];
  unsigned short* WT = Tt[blockIdx.z];
  __shared__ float tile[32][33];
  const int tx = threadIdx.x & 31;
  const int ty = threadIdx.x >> 5;
  const int x0 = blockIdx.x * 32;
  const int y0 = blockIdx.y * 32;
#pragma unroll
  for (int i = 0; i < 32; i += 8)
    tile[ty + i][tx] = W[(size_t)(y0 + ty + i) * DM + x0 + tx];
  __syncthreads();
#pragma unroll
  for (int i = 0; i < 32; i += 8)
    WT[(size_t)(x0 + ty + i) * DM + y0 + tx] = f2bf(tile[tx][ty + i]);
}

// ---------------------------------------------------------------------------
// fp32 -> bf16 convert, 8 elems/thread, vectorized (single and 3-src merged)
// ---------------------------------------------------------------------------
__global__ __launch_bounds__(256) void cvt_bf16_kernel(
    const float* __restrict__ x, unsigned short* __restrict__ y) {
  const size_t i = ((size_t)blockIdx.x * 256 + threadIdx.x) * 8;
  float4 a = *(const float4*)(x + i);
  float4 b = *(const float4*)(x + i + 4);
  uint4 p = {pack2(a.x, a.y), pack2(a.z, a.w), pack2(b.x, b.y), pack2(b.z, b.w)};
  *(uint4*)(y + i) = p;
}

__global__ __launch_bounds__(256) void cvt3_bf16_kernel(
    const float* __restrict__ q, const float* __restrict__ k,
    const float* __restrict__ v, unsigned short* __restrict__ Xq,
    unsigned short* __restrict__ Xk, unsigned short* __restrict__ Xv) {
  const int z = blockIdx.y;
  const float* x = (z == 0) ? q : (z == 1) ? k : v;
  unsigned short* y = (z == 0) ? Xq : (z == 1) ? Xk : Xv;
  const size_t i = ((size_t)blockIdx.x * 256 + threadIdx.x) * 8;
  float4 a = *(const float4*)(x + i);
  float4 b = *(const float4*)(x + i + 4);
  uint4 p = {pack2(a.x, a.y), pack2(a.z, a.w), pack2(b.x, b.y), pack2(b.z, b.w)};
  *(uint4*)(y + i) = p;
}

// ---------------------------------------------------------------------------
// GEMM body (m97 structure, BK=32): C = A(8192x1024 bf16) * BT^T + bias.
// 128x128 tile, 256 thr (4 waves, 4x4 16x16x32 frags).
// Staging via global_load_lds width-16 into LINEAR LDS [128][32] (16 KB).
// OUTMODE 0: bf16 out scaled, head layout [B,H,L,DH].
// OUTMODE 1: fp32 row-major.
// OUTMODE 2: bf16 out, TRANSPOSED head layout [B,H,DH,L]  (for V)
// Bijective XCD swizzle over the (x,y) grid (nwg % 8 == 0).
// ---------------------------------------------------------------------------
template <int OUTMODE>
__device__ __forceinline__ void gemm_body32(
    const unsigned short* __restrict__ A, const unsigned short* __restrict__ BT,
    const float* __restrict__ bias, void* __restrict__ Cptr, float scale) {
  constexpr int K = DM, N = DM;
  __shared__ unsigned short As[128 * 32];
  __shared__ unsigned short Bs[128 * 32];
  const int t = threadIdx.x;
  const int lane = t & 63;
  const int w = t >> 6;
  const int wr = w >> 1, wc = w & 1;
  const int fr = lane & 15, kg = lane >> 4;

  // XCD-aware swizzle: consecutive swz within an XCD share A row-panels
  const int flat = blockIdx.y * gridDim.x + blockIdx.x;
  const int cpx = (gridDim.x * gridDim.y) >> 3;  // nwg/8, nwg%8==0
  const int swz = (flat & 7) * cpx + (flat >> 3);
  const int m0 = (swz / gridDim.x) * 128;
  const int n0 = (swz % gridDim.x) * 128;

  // staging: lane covers row (lane>>2), col-chunk (lane&3)*8 of a [64][32] half
  const int grow = lane >> 2, gcol8 = (lane & 3) * 8;

  f32x4 acc[4][4] = {};

  for (int kt = 0; kt < K / 32; ++kt) {
    const int k0 = kt * 32;
#pragma unroll
    for (int i = 0; i < 2; i++) {
      gload16(A + (size_t)(m0 + i * 64 + w * 16 + grow) * K + k0 + gcol8,
              &As[(i * 256 + w * 64 + lane) * 8]);
      gload16(BT + (size_t)(n0 + i * 64 + w * 16 + grow) * K + k0 + gcol8,
              &Bs[(i * 256 + w * 64 + lane) * 8]);
    }
    __syncthreads();  // drains vmcnt -> LDS tiles complete

    bf16x8 af[4], bfr[4];
#pragma unroll
    for (int i = 0; i < 4; i++)
      af[i] = *(const bf16x8*)&As[(wr * 64 + i * 16 + fr) * 32 + kg * 8];
#pragma unroll
    for (int i = 0; i < 4; i++)
      bfr[i] = *(const bf16x8*)&Bs[(wc * 64 + i * 16 + fr) * 32 + kg * 8];
#pragma unroll
    for (int i = 0; i < 4; i++)
#pragma unroll
      for (int j = 0; j < 4; j++)
        acc[i][j] = __builtin_amdgcn_mfma_f32_16x16x32_bf16(af[i], bfr[j], acc[i][j], 0, 0, 0);
    __syncthreads();
  }

#pragma unroll
  for (int j = 0; j < 4; j++) {
    const int gcol = n0 + wc * 64 + j * 16 + fr;
    const float bv = bias[gcol];
    const int h = gcol >> 6, dh = gcol & 63;
#pragma unroll
    for (int i = 0; i < 4; i++) {
      const int grow0 = m0 + wr * 64 + i * 16 + kg * 4;
      if (OUTMODE == 2) {
        const int b = grow0 >> 11, l = grow0 & 2047;
        uint2 pk;
        pk.x = pack2(acc[i][j][0] + bv, acc[i][j][1] + bv);
        pk.y = pack2(acc[i][j][2] + bv, acc[i][j][3] + bv);
        *(uint2*)((unsigned short*)Cptr +
                  ((size_t)((b * HEADS + h) * DH + dh)) * LL + l) = pk;
      } else {
#pragma unroll
        for (int r = 0; r < 4; r++) {
          const int grow2 = grow0 + r;
          if (OUTMODE == 0) {
            const float val = (acc[i][j][r] + bv) * scale;
            const int b = grow2 >> 11, l = grow2 & 2047;
            ((unsigned short*)Cptr)[(((size_t)(b * HEADS + h) * LL + l) << 6) + dh] = f2bf(val);
          } else {
            ((float*)Cptr)[(size_t)grow2 * N + gcol] = acc[i][j][r] + bv;
          }
        }
      }
    }
  }
}

// scale = 0.125 * log2(e) folded into Q so attention softmax can use exp2
#define QSCALE 0.18033688011112042f

// QKV projection: z = blockIdx.z + zoff selects {Q,K,V}.
__global__ __launch_bounds__(256) void qkv_gemm_kernel(
    const unsigned short* __restrict__ A0, size_t strideA,
    const unsigned short* __restrict__ WT0,
    const float* __restrict__ bq, const float* __restrict__ bk,
    const float* __restrict__ bv, unsigned short* __restrict__ O0, int zoff) {
  const int z = (int)blockIdx.z + zoff;
  const unsigned short* A = A0 + (size_t)z * strideA;
  const unsigned short* BT = WT0 + (size_t)z * DM * DM;
  const float* bias = (z == 0) ? bq : (z == 1) ? bk : bv;
  unsigned short* C = O0 + (size_t)z * MROWS * DM;
  if (z == 2)
    gemm_body32<2>(A, BT, bias, C, 1.0f);
  else
    gemm_body32<0>(A, BT, bias, C, (z == 0) ? QSCALE : 1.0f);
}

__global__ __launch_bounds__(256) void oproj_gemm_kernel(
    const unsigned short* __restrict__ Oc, const unsigned short* __restrict__ WoT,
    const float* __restrict__ bo, float* __restrict__ out) {
  gemm_body32<1>(Oc, WoT, bo, out, 1.0f);
}

// ---------------------------------------------------------------------------
// Causal flash attention, swapped-operand 32x32x16, 4-wave / 256-thr blocks.
// (round-11 form: LDS double-buffered staging restored -- the staging IS the
// coalescer; round-12's direct-global version spilled + uncoalesced, 4x.)
// Grid (16, 64) = 1024 blocks, ONE q-tile (128 rows) per block.
// LDS 38.9KB/block (PAD 76) -> 4 blocks/CU (155.6 of 160 KB), 16 waves/CU.
// CU-balanced zigzag mapping (dispatch CU ~ f&255, layer = f>>8):
//   qi = {sub, 7-sub, 8+sub, 15-sub}[layer] -> per-CU qi sum = 30 (uniform
//   68 tile-iters/CU); each XCD owns 8 bh (KV set 4MB = one L2).
// Per wave: 32 q-rows; KV tiles of 64; Dh = 64.
// Double-buffered K/V LDS, 1 barrier/iter, reg prefetch before barrier.
// Defer-max rescale skip; stride 76 (38 words, bank-stride 6) -> 2-way (free).
// ---------------------------------------------------------------------------
#define PAD 76
__global__ __launch_bounds__(256, 4) void attn_kernel(
    const unsigned short* __restrict__ Qh, const unsigned short* __restrict__ Kh,
    const unsigned short* __restrict__ VhT, unsigned short* __restrict__ O) {
  __shared__ unsigned short Ks[2][64][PAD];
  __shared__ unsigned short VTs[2][64][PAD];  // [dh][kv]
  const int t = threadIdx.x, lane = t & 63, w = t >> 6;  // w in 0..3
  const int lo5 = lane & 31, hi = lane >> 5;

  // CU-balanced, XCD-local decode
  const int f = (int)(blockIdx.y * gridDim.x + blockIdx.x);  // 0..1023
  const int l = f >> 8;        // co-resident layer 0..3
  const int c = f & 255;       // CU slot
  const int xcd = c & 7, j = c >> 3;
  const int bh = xcd * 8 + (j & 7);
  const int sub = j >> 3;      // 0..3
  const int qi = (l == 0) ? sub : (l == 1) ? 7 - sub : (l == 2) ? 8 + sub : 15 - sub;

  const size_t base = (size_t)bh * LL * DH;
  const unsigned short* Kb = Kh + base;
  const unsigned short* Vb = VhT + base;  // [dh][l]

  // staging: [64][64] bf16 tile, 256 threads x two 8-elem chunks per matrix
  const int rA = t >> 3, kA = (t & 7) * 8;  // rows 0..31
  const int rB = rA + 32;                   // rows 32..63

  const int b = bh >> 4, h = bh & 15;

  const int q0 = qi * 128;
  const int qrow = q0 + w * 32 + lo5;  // this lane's q row

  // Q fragments: B-operand, col = q = lane&31, k = kc*16 + hi*8 + j
  bf16x8 qf[4];
  {
    const unsigned short* Qb = Qh + base + (size_t)qrow * DH + hi * 8;
#pragma unroll
    for (int kc = 0; kc < 4; kc++) qf[kc] = *(const bf16x8*)(Qb + kc * 16);
  }

  float m_run = -INFINITY, l_run = 0.f;
  f32x16 oacc[2] = {};  // D[dh][q]

  const int ntiles = 2 * (qi + 1);
  const int my_last = (q0 + w * 32 + 31) >> 6;  // last tile this wave needs

  // prologue: tile 0 -> regs -> buf0 (first loop barrier publishes it)
  uint4 kr0 = *(const uint4*)(Kb + (size_t)rA * DH + kA);
  uint4 kr1 = *(const uint4*)(Kb + (size_t)rB * DH + kA);
  uint4 vr0 = *(const uint4*)(Vb + (size_t)rA * LL + kA);
  uint4 vr1 = *(const uint4*)(Vb + (size_t)rB * LL + kA);
  *(uint4*)&Ks[0][rA][kA] = kr0;
  *(uint4*)&Ks[0][rB][kA] = kr1;
  *(uint4*)&VTs[0][rA][kA] = vr0;
  *(uint4*)&VTs[0][rB][kA] = vr1;

  for (int jt = 0; jt < ntiles; ++jt) {
    const int cur = jt & 1;
    // issue next tile's global loads (consumed after compute)
    if (jt + 1 < ntiles) {
      const int kv1 = (jt + 1) * 64;
      kr0 = *(const uint4*)(Kb + (size_t)(kv1 + rA) * DH + kA);
      kr1 = *(const uint4*)(Kb + (size_t)(kv1 + rB) * DH + kA);
      vr0 = *(const uint4*)(Vb + (size_t)rA * LL + kv1 + kA);
      vr1 = *(const uint4*)(Vb + (size_t)rB * LL + kv1 + kA);
    }
    __syncthreads();  // buf[cur] writes from prev iter visible

    if (jt <= my_last) {
      // S^T = K * Q^T : two 32x32 tiles along kv, K-dim = Dh = 64
      f32x16 s2[2] = {};
      __builtin_amdgcn_s_setprio(1);
#pragma unroll
      for (int tt = 0; tt < 2; tt++)
#pragma unroll
        for (int kc = 0; kc < 4; kc++) {
          bf16x8 kf = *(const bf16x8*)&Ks[cur][tt * 32 + lo5][kc * 16 + hi * 8];
          s2[tt] = __builtin_amdgcn_mfma_f32_32x32x16_bf16(kf, qf[kc], s2[tt], 0, 0, 0);
        }
      __builtin_amdgcn_s_setprio(0);

      // causal mask (only tiles overlapping this wave's diagonal)
      const int kv0 = jt * 64;
      if (kv0 + 63 > q0 + w * 32) {
        const int thr = qrow - kv0 - 4 * hi;
#pragma unroll
        for (int tt = 0; tt < 2; tt++)
#pragma unroll
          for (int i = 0; i < 16; i++) {
            const int kvoff = tt * 32 + (i & 3) + 8 * (i >> 2);
            s2[tt][i] = (kvoff > thr) ? -1e30f : s2[tt][i];
          }
      }

      // row max: in-lane tree (max3-friendly nesting) + cross-half shfl
      float mx;
      {
        float m8[8];
#pragma unroll
        for (int i = 0; i < 8; i++)
          m8[i] = fmaxf(fmaxf(s2[0][i], s2[0][i + 8]), fmaxf(s2[1][i], s2[1][i + 8]));
        const float a3 = fmaxf(fmaxf(m8[0], m8[1]), m8[2]);
        const float b3 = fmaxf(fmaxf(m8[3], m8[4]), m8[5]);
        const float c3 = fmaxf(m8[6], m8[7]);
        mx = fmaxf(fmaxf(a3, b3), c3);
      }
      mx = fmaxf(mx, __shfl_xor(mx, 32));

      // defer-max: only rescale when some row's max grew by >8 (2^8 P-bound)
      if (__any(mx > m_run + 8.0f)) {
        const float mnew = fmaxf(m_run, mx);
        const float corr = __builtin_amdgcn_exp2f(m_run - mnew);
        m_run = mnew;
        l_run *= corr;
#pragma unroll
        for (int od = 0; od < 2; od++)
#pragma unroll
          for (int i = 0; i < 16; i++) oacc[od][i] *= corr;
      }

      // p = exp2(s - m)   (logits pre-scaled by log2e at the Q projection)
#pragma unroll
      for (int tt = 0; tt < 2; tt++)
#pragma unroll
        for (int i = 0; i < 16; i++)
          s2[tt][i] = __builtin_amdgcn_exp2f(s2[tt][i] - m_run);

      // row sum: in-lane tree + cross-half shfl
      float rs;
      {
        float a8[8];
#pragma unroll
        for (int i = 0; i < 8; i++)
          a8[i] = (s2[0][i] + s2[0][i + 8]) + (s2[1][i] + s2[1][i + 8]);
#pragma unroll
        for (int st = 4; st > 0; st >>= 1)
#pragma unroll
          for (int i = 0; i < st; i++) a8[i] += a8[i + st];
        rs = a8[0];
      }
      rs += __shfl_xor(rs, 32);
      l_run += rs;

      // build P B-operand fragments: pa[ks] holds kv = ks*16 + hi*8 + j
      union U8 { uint4 u; bf16x8 v; } pa[4];
#pragma unroll
      for (int ks = 0; ks < 4; ks++) {
        const int tt = ks >> 1, b0 = (ks & 1) * 8;
        const unsigned int w0 = pack2(s2[tt][b0 + 0], s2[tt][b0 + 1]);
        const unsigned int w1 = pack2(s2[tt][b0 + 2], s2[tt][b0 + 3]);
        const unsigned int w2 = pack2(s2[tt][b0 + 4], s2[tt][b0 + 5]);
        const unsigned int w3 = pack2(s2[tt][b0 + 6], s2[tt][b0 + 7]);
        const unsigned int p0 = (unsigned int)__shfl_xor((int)w0, 32);
        const unsigned int p1 = (unsigned int)__shfl_xor((int)w1, 32);
        const unsigned int p2 = (unsigned int)__shfl_xor((int)w2, 32);
        const unsigned int p3 = (unsigned int)__shfl_xor((int)w3, 32);
        pa[ks].u = hi ? make_uint4(p2, p3, w2, w3) : make_uint4(w0, w1, p0, p1);
      }

      // O^T += VT * P : D[dh][q]
      __builtin_amdgcn_s_setprio(1);
#pragma unroll
      for (int od = 0; od < 2; od++)
#pragma unroll
        for (int ks = 0; ks < 4; ks++) {
          bf16x8 vf = *(const bf16x8*)&VTs[cur][od * 32 + lo5][ks * 16 + hi * 8];
          oacc[od] = __builtin_amdgcn_mfma_f32_32x32x16_bf16(vf, pa[ks].v, oacc[od], 0, 0, 0);
        }
      __builtin_amdgcn_s_setprio(0);
    }

    // stage next tile into the other buffer (visible after next barrier)
    if (jt + 1 < ntiles) {
      *(uint4*)&Ks[cur ^ 1][rA][kA] = kr0;
      *(uint4*)&Ks[cur ^ 1][rB][kA] = kr1;
      *(uint4*)&VTs[cur ^ 1][rA][kA] = vr0;
      *(uint4*)&VTs[cur ^ 1][rB][kA] = vr1;
    }
  }

  // epilogue: O[b][l][h*64+dh] bf16; lane's q = qrow, dh = crow+od*32
  const float linv = 1.f / l_run;
  unsigned short* Ob = O + ((size_t)(b * LL + qrow) * DM) + h * DH;
#pragma unroll
  for (int od = 0; od < 2; od++)
#pragma unroll
    for (int m = 0; m < 8; m++) {
      const int dh0 = od * 32 + ((2 * m) & 3) + 8 * ((2 * m) >> 2) + 4 * hi;
      const unsigned int pk =
          pack2(oacc[od][2 * m] * linv, oacc[od][2 * m + 1] * linv);
      *(unsigned int*)(Ob + dh0) = pk;
    }
}

// ---------------------------------------------------------------------------
extern "C" void kernel_launch(void* const* d_in, const int* in_sizes, int n_in,
                              void* d_out, int out_size, void* d_ws, size_t ws_size,
                              hipStream_t stream) {
  (void)in_sizes; (void)n_in; (void)out_size;
  const float* q  = (const float*)d_in[0];
  const float* k  = (const float*)d_in[1];
  const float* v  = (const float*)d_in[2];
  const float* Wq = (const float*)d_in[3];
  const float* bq = (const float*)d_in[4];
  const float* Wk = (const float*)d_in[5];
  const float* bk = (const float*)d_in[6];
  const float* Wv = (const float*)d_in[7];
  const float* bv = (const float*)d_in[8];
  const float* Wo = (const float*)d_in[9];
  const float* bo = (const float*)d_in[10];

  char* ws = (char*)d_ws;
  const size_t WSZ = (size_t)DM * DM * 2;     // 2 MB per transposed weight
  const size_t HSZ = (size_t)MROWS * DM * 2;  // 16 MB per bf16 activation
  unsigned short* WT0 = (unsigned short*)(ws);             // WqT,WkT,WvT,WoT contiguous
  unsigned short* WoT = (unsigned short*)(ws + 3 * WSZ);
  unsigned short* Qh  = (unsigned short*)(ws + 4 * WSZ);   // Qh,Kh,VhT contiguous
  unsigned short* Kh  = (unsigned short*)(ws + 4 * WSZ + HSZ);
  unsigned short* VhT = (unsigned short*)(ws + 4 * WSZ + 2 * HSZ);
  unsigned short* X   = (unsigned short*)(ws + 4 * WSZ + 3 * HSZ);  // scratch, later Oc
  unsigned short* Oc  = X;  // X's contents dead once V-GEMM finishes

  transpose_w_kernel<<<dim3(32, 32, 4), 256, 0, stream>>>(
      Wq, Wk, Wv, Wo,
      WT0, WT0 + DM * DM, WT0 + 2 * (size_t)DM * DM, WoT);

  const dim3 cgrid(MROWS * DM / (256 * 8));
  const dim3 ggrid(DM / 128, MROWS / 128);
  const size_t NEED = 4 * WSZ + 6 * HSZ;  // 3 extra X buffers

  if (ws_size >= NEED) {
    // merged path: Xq,Xk,Xv separate -> one cvt launch + one QKV-GEMM launch
    unsigned short* Xq = X;
    unsigned short* Xk = X + (size_t)MROWS * DM;
    unsigned short* Xv = X + 2 * (size_t)MROWS * DM;
    cvt3_bf16_kernel<<<dim3(MROWS * DM / (256 * 8), 3), 256, 0, stream>>>(
        q, k, v, Xq, Xk, Xv);
    qkv_gemm_kernel<<<dim3(DM / 128, MROWS / 128, 3), 256, 0, stream>>>(
        Xq, (size_t)MROWS * DM, WT0, bq, bk, bv, Qh, 0);
  } else {
    // serial path: shared 16MB scratch
    cvt_bf16_kernel<<<cgrid, 256, 0, stream>>>(q, X);
    qkv_gemm_kernel<<<ggrid, 256, 0, stream>>>(X, 0, WT0, bq, bk, bv, Qh, 0);
    cvt_bf16_kernel<<<cgrid, 256, 0, stream>>>(k, X);
    qkv_gemm_kernel<<<ggrid, 256, 0, stream>>>(X, 0, WT0, bq, bk, bv, Qh, 1);
    cvt_bf16_kernel<<<cgrid, 256, 0, stream>>>(v, X);
    qkv_gemm_kernel<<<ggrid, 256, 0, stream>>>(X, 0, WT0, bq, bk, bv, Qh, 2);
  }

  attn_kernel<<<dim3(16, BB * HEADS), 256, 0, stream>>>(Qh, Kh, VhT, Oc);

  oproj_gemm_kernel<<<ggrid, 256, 0, stream>>>(Oc, WoT, bo, (float*)d_out);
}

// Round 15
// 194.917 us; speedup vs baseline: 2.2041x; 1.0246x over previous
//
#include <hip/hip_runtime.h>

#define DM 1024
#define HEADS 16
#define DH 64
#define BB 4
#define LL 2048
#define MROWS (BB * LL) /* 8192 */

typedef __bf16 bf16x8 __attribute__((ext_vector_type(8)));
typedef float f32x4 __attribute__((ext_vector_type(4)));
typedef float f32x16 __attribute__((ext_vector_type(16)));

// HW round-to-nearest-even f32->bf16 via compiler (emits v_cvt_pk_bf16_f32)
__device__ __forceinline__ unsigned short f2bf(float f) {
  __bf16 h = (__bf16)f;
  return __builtin_bit_cast(unsigned short, h);
}
__device__ __forceinline__ unsigned int pack2(float a, float b) {
  return (unsigned int)f2bf(a) | ((unsigned int)f2bf(b) << 16);
}

// async global->LDS, 16B per lane; LDS dest is wave-uniform base + lane*16
__device__ __forceinline__ void gload16(const unsigned short* g, unsigned short* l) {
  __builtin_amdgcn_global_load_lds(
      (const __attribute__((address_space(1))) unsigned int*)(const void*)g,
      (__attribute__((address_space(3))) unsigned int*)(void*)l, 16, 0, 0);
}

// ---------------------------------------------------------------------------
// Weight transpose + bf16 convert: WT[n][k] = bf16(W[k][n]), 1024x1024, z=4
// (standalone version, used in the serial fallback path)
// ---------------------------------------------------------------------------
__global__ __launch_bounds__(256) void transpose_w_kernel(
    const float* __restrict__ W0, const float* __restrict__ W1,
    const float* __restrict__ W2, const float* __restrict__ W3,
    unsigned short* __restrict__ T0, unsigned short* __restrict__ T1,
    unsigned short* __restrict__ T2, unsigned short* __restrict__ T3) {
  const float* Wt[4] = {W0, W1, W2, W3};
  unsigned short* Tt[4] = {T0, T1, T2, T3};
  const float* W = Wt[blockIdx.z];
  unsigned short* WT = Tt[blockIdx.z];
  __shared__ float tile[32][33];
  const int tx = threadIdx.x & 31;
  const int ty = threadIdx.x >> 5;
  const int x0 = blockIdx.x * 32;
  const int y0 = blockIdx.y * 32;
#pragma unroll
  for (int i = 0; i < 32; i += 8)
    tile[ty + i][tx] = W[(size_t)(y0 + ty + i) * DM + x0 + tx];
  __syncthreads();
#pragma unroll
  for (int i = 0; i < 32; i += 8)
    WT[(size_t)(x0 + ty + i) * DM + y0 + tx] = f2bf(tile[tx][ty + i]);
}

// ---------------------------------------------------------------------------
// fp32 -> bf16 convert, 8 elems/thread (serial fallback path)
// ---------------------------------------------------------------------------
__global__ __launch_bounds__(256) void cvt_bf16_kernel(
    const float* __restrict__ x, unsigned short* __restrict__ y) {
  const size_t i = ((size_t)blockIdx.x * 256 + threadIdx.x) * 8;
  float4 a = *(const float4*)(x + i);
  float4 b = *(const float4*)(x + i + 4);
  uint4 p = {pack2(a.x, a.y), pack2(a.z, a.w), pack2(b.x, b.y), pack2(b.z, b.w)};
  *(uint4*)(y + i) = p;
}

// ---------------------------------------------------------------------------
// Merged prep: blocks [0,12288) = cvt of q/k/v (4096 each);
//              blocks [12288,16384) = the 4 weight transposes (1024 each).
// One launch instead of two -> less serialized launch overhead.
// ---------------------------------------------------------------------------
__global__ __launch_bounds__(256) void prep_kernel(
    const float* __restrict__ q, const float* __restrict__ k,
    const float* __restrict__ v, unsigned short* __restrict__ Xq,
    unsigned short* __restrict__ Xk, unsigned short* __restrict__ Xv,
    const float* __restrict__ W0, const float* __restrict__ W1,
    const float* __restrict__ W2, const float* __restrict__ W3,
    unsigned short* __restrict__ T0, unsigned short* __restrict__ T1,
    unsigned short* __restrict__ T2, unsigned short* __restrict__ T3) {
  __shared__ float tile[32][33];
  const int bid = (int)blockIdx.x;
  if (bid < 12288) {
    const int z = bid >> 12;           // tensor 0..2
    const int chunk = bid & 4095;
    const float* x = (z == 0) ? q : (z == 1) ? k : v;
    unsigned short* y = (z == 0) ? Xq : (z == 1) ? Xk : Xv;
    const size_t i = ((size_t)chunk * 256 + threadIdx.x) * 8;
    float4 a = *(const float4*)(x + i);
    float4 b = *(const float4*)(x + i + 4);
    uint4 p = {pack2(a.x, a.y), pack2(a.z, a.w), pack2(b.x, b.y), pack2(b.z, b.w)};
    *(uint4*)(y + i) = p;
  } else {
    const int tb = bid - 12288;        // 0..4095
    const int wz = tb >> 10;           // weight 0..3
    const int rem = tb & 1023;
    const float* Wt[4] = {W0, W1, W2, W3};
    unsigned short* Tt[4] = {T0, T1, T2, T3};
    const float* W = Wt[wz];
    unsigned short* WT = Tt[wz];
    const int tx = threadIdx.x & 31;
    const int ty = threadIdx.x >> 5;
    const int x0 = (rem & 31) * 32;
    const int y0 = (rem >> 5) * 32;
#pragma unroll
    for (int i = 0; i < 32; i += 8)
      tile[ty + i][tx] = W[(size_t)(y0 + ty + i) * DM + x0 + tx];
    __syncthreads();
#pragma unroll
    for (int i = 0; i < 32; i += 8)
      WT[(size_t)(x0 + ty + i) * DM + y0 + tx] = f2bf(tile[tx][ty + i]);
  }
}

// ---------------------------------------------------------------------------
// GEMM body (m97 structure, BK=32): C = A(8192x1024 bf16) * BT^T + bias.
// 128x128 tile, 256 thr (4 waves, 4x4 16x16x32 frags).
// Staging via global_load_lds width-16 into LINEAR LDS [128][32] (16 KB).
// OUTMODE 0: bf16 out scaled, head layout [B,H,L,DH].
// OUTMODE 1: fp32 row-major.
// OUTMODE 2: bf16 out, TRANSPOSED head layout [B,H,DH,L]  (for V)
// Bijective XCD swizzle over the (x,y) grid (nwg % 8 == 0).
// ---------------------------------------------------------------------------
template <int OUTMODE>
__device__ __forceinline__ void gemm_body32(
    const unsigned short* __restrict__ A, const unsigned short* __restrict__ BT,
    const float* __restrict__ bias, void* __restrict__ Cptr, float scale) {
  constexpr int K = DM, N = DM;
  __shared__ unsigned short As[128 * 32];
  __shared__ unsigned short Bs[128 * 32];
  const int t = threadIdx.x;
  const int lane = t & 63;
  const int w = t >> 6;
  const int wr = w >> 1, wc = w & 1;
  const int fr = lane & 15, kg = lane >> 4;

  // XCD-aware swizzle: consecutive swz within an XCD share A row-panels
  const int flat = blockIdx.y * gridDim.x + blockIdx.x;
  const int cpx = (gridDim.x * gridDim.y) >> 3;  // nwg/8, nwg%8==0
  const int swz = (flat & 7) * cpx + (flat >> 3);
  const int m0 = (swz / gridDim.x) * 128;
  const int n0 = (swz % gridDim.x) * 128;

  // staging: lane covers row (lane>>2), col-chunk (lane&3)*8 of a [64][32] half
  const int grow = lane >> 2, gcol8 = (lane & 3) * 8;

  f32x4 acc[4][4] = {};

  for (int kt = 0; kt < K / 32; ++kt) {
    const int k0 = kt * 32;
#pragma unroll
    for (int i = 0; i < 2; i++) {
      gload16(A + (size_t)(m0 + i * 64 + w * 16 + grow) * K + k0 + gcol8,
              &As[(i * 256 + w * 64 + lane) * 8]);
      gload16(BT + (size_t)(n0 + i * 64 + w * 16 + grow) * K + k0 + gcol8,
              &Bs[(i * 256 + w * 64 + lane) * 8]);
    }
    __syncthreads();  // drains vmcnt -> LDS tiles complete

    bf16x8 af[4], bfr[4];
#pragma unroll
    for (int i = 0; i < 4; i++)
      af[i] = *(const bf16x8*)&As[(wr * 64 + i * 16 + fr) * 32 + kg * 8];
#pragma unroll
    for (int i = 0; i < 4; i++)
      bfr[i] = *(const bf16x8*)&Bs[(wc * 64 + i * 16 + fr) * 32 + kg * 8];
#pragma unroll
    for (int i = 0; i < 4; i++)
#pragma unroll
      for (int j = 0; j < 4; j++)
        acc[i][j] = __builtin_amdgcn_mfma_f32_16x16x32_bf16(af[i], bfr[j], acc[i][j], 0, 0, 0);
    __syncthreads();
  }

#pragma unroll
  for (int j = 0; j < 4; j++) {
    const int gcol = n0 + wc * 64 + j * 16 + fr;
    const float bv = bias[gcol];
    const int h = gcol >> 6, dh = gcol & 63;
#pragma unroll
    for (int i = 0; i < 4; i++) {
      const int grow0 = m0 + wr * 64 + i * 16 + kg * 4;
      if (OUTMODE == 2) {
        const int b = grow0 >> 11, l = grow0 & 2047;
        uint2 pk;
        pk.x = pack2(acc[i][j][0] + bv, acc[i][j][1] + bv);
        pk.y = pack2(acc[i][j][2] + bv, acc[i][j][3] + bv);
        *(uint2*)((unsigned short*)Cptr +
                  ((size_t)((b * HEADS + h) * DH + dh)) * LL + l) = pk;
      } else {
#pragma unroll
        for (int r = 0; r < 4; r++) {
          const int grow2 = grow0 + r;
          if (OUTMODE == 0) {
            const float val = (acc[i][j][r] + bv) * scale;
            const int b = grow2 >> 11, l = grow2 & 2047;
            ((unsigned short*)Cptr)[(((size_t)(b * HEADS + h) * LL + l) << 6) + dh] = f2bf(val);
          } else {
            ((float*)Cptr)[(size_t)grow2 * N + gcol] = acc[i][j][r] + bv;
          }
        }
      }
    }
  }
}

// scale = 0.125 * log2(e) folded into Q so attention softmax can use exp2
#define QSCALE 0.18033688011112042f

// QKV projection: z = blockIdx.z + zoff selects {Q,K,V}.
__global__ __launch_bounds__(256) void qkv_gemm_kernel(
    const unsigned short* __restrict__ A0, size_t strideA,
    const unsigned short* __restrict__ WT0,
    const float* __restrict__ bq, const float* __restrict__ bk,
    const float* __restrict__ bv, unsigned short* __restrict__ O0, int zoff) {
  const int z = (int)blockIdx.z + zoff;
  const unsigned short* A = A0 + (size_t)z * strideA;
  const unsigned short* BT = WT0 + (size_t)z * DM * DM;
  const float* bias = (z == 0) ? bq : (z == 1) ? bk : bv;
  unsigned short* C = O0 + (size_t)z * MROWS * DM;
  if (z == 2)
    gemm_body32<2>(A, BT, bias, C, 1.0f);
  else
    gemm_body32<0>(A, BT, bias, C, (z == 0) ? QSCALE : 1.0f);
}

__global__ __launch_bounds__(256) void oproj_gemm_kernel(
    const unsigned short* __restrict__ Oc, const unsigned short* __restrict__ WoT,
    const float* __restrict__ bo, float* __restrict__ out) {
  gemm_body32<1>(Oc, WoT, bo, out, 1.0f);
}

// ---------------------------------------------------------------------------
// Causal flash attention, swapped-operand 32x32x16, 4-wave / 256-thr blocks.
// (round-13-verified body: shfl_xor for cross-half exchange and P-pack;
// permlane reverted entirely -- r8 asm and r14 builtin both failed, its
// lane-layout on this toolchain is unverified.)
// Grid (16, 64) = 1024 blocks, ONE q-tile (128 rows) per block.
// LDS 38.9KB/block (PAD 76) -> 4 blocks/CU, 16 waves/CU peak.
// CU-balanced zigzag mapping; each XCD owns 8 bh (KV set 4MB = one L2).
// Double-buffered K/V LDS, 1 barrier/iter, reg prefetch before barrier.
// Defer-max rescale skip; stride 76 -> 2-way bank aliasing (free).
// ---------------------------------------------------------------------------
#define PAD 76
__global__ __launch_bounds__(256, 4) void attn_kernel(
    const unsigned short* __restrict__ Qh, const unsigned short* __restrict__ Kh,
    const unsigned short* __restrict__ VhT, unsigned short* __restrict__ O) {
  __shared__ unsigned short Ks[2][64][PAD];
  __shared__ unsigned short VTs[2][64][PAD];  // [dh][kv]
  const int t = threadIdx.x, lane = t & 63, w = t >> 6;  // w in 0..3
  const int lo5 = lane & 31, hi = lane >> 5;

  // CU-balanced, XCD-local decode
  const int f = (int)(blockIdx.y * gridDim.x + blockIdx.x);  // 0..1023
  const int l = f >> 8;        // co-resident layer 0..3
  const int c = f & 255;       // CU slot
  const int xcd = c & 7, j = c >> 3;
  const int bh = xcd * 8 + (j & 7);
  const int sub = j >> 3;      // 0..3
  const int qi = (l == 0) ? sub : (l == 1) ? 7 - sub : (l == 2) ? 8 + sub : 15 - sub;

  const size_t base = (size_t)bh * LL * DH;
  const unsigned short* Kb = Kh + base;
  const unsigned short* Vb = VhT + base;  // [dh][l]

  // staging: [64][64] bf16 tile, 256 threads x two 8-elem chunks per matrix
  const int rA = t >> 3, kA = (t & 7) * 8;  // rows 0..31
  const int rB = rA + 32;                   // rows 32..63

  const int b = bh >> 4, h = bh & 15;

  const int q0 = qi * 128;
  const int qrow = q0 + w * 32 + lo5;  // this lane's q row

  // Q fragments: B-operand, col = q = lane&31, k = kc*16 + hi*8 + j
  bf16x8 qf[4];
  {
    const unsigned short* Qb = Qh + base + (size_t)qrow * DH + hi * 8;
#pragma unroll
    for (int kc = 0; kc < 4; kc++) qf[kc] = *(const bf16x8*)(Qb + kc * 16);
  }

  float m_run = -INFINITY, l_run = 0.f;
  f32x16 oacc[2] = {};  // D[dh][q]

  const int ntiles = 2 * (qi + 1);
  const int my_last = (q0 + w * 32 + 31) >> 6;  // last tile this wave needs

  // prologue: tile 0 -> regs -> buf0 (first loop barrier publishes it)
  uint4 kr0 = *(const uint4*)(Kb + (size_t)rA * DH + kA);
  uint4 kr1 = *(const uint4*)(Kb + (size_t)rB * DH + kA);
  uint4 vr0 = *(const uint4*)(Vb + (size_t)rA * LL + kA);
  uint4 vr1 = *(const uint4*)(Vb + (size_t)rB * LL + kA);
  *(uint4*)&Ks[0][rA][kA] = kr0;
  *(uint4*)&Ks[0][rB][kA] = kr1;
  *(uint4*)&VTs[0][rA][kA] = vr0;
  *(uint4*)&VTs[0][rB][kA] = vr1;

  for (int jt = 0; jt < ntiles; ++jt) {
    const int cur = jt & 1;
    // issue next tile's global loads (consumed after compute)
    if (jt + 1 < ntiles) {
      const int kv1 = (jt + 1) * 64;
      kr0 = *(const uint4*)(Kb + (size_t)(kv1 + rA) * DH + kA);
      kr1 = *(const uint4*)(Kb + (size_t)(kv1 + rB) * DH + kA);
      vr0 = *(const uint4*)(Vb + (size_t)rA * LL + kv1 + kA);
      vr1 = *(const uint4*)(Vb + (size_t)rB * LL + kv1 + kA);
    }
    __syncthreads();  // buf[cur] writes from prev iter visible

    if (jt <= my_last) {
      // S^T = K * Q^T : two 32x32 tiles along kv, K-dim = Dh = 64
      f32x16 s2[2] = {};
      __builtin_amdgcn_s_setprio(1);
#pragma unroll
      for (int tt = 0; tt < 2; tt++)
#pragma unroll
        for (int kc = 0; kc < 4; kc++) {
          bf16x8 kf = *(const bf16x8*)&Ks[cur][tt * 32 + lo5][kc * 16 + hi * 8];
          s2[tt] = __builtin_amdgcn_mfma_f32_32x32x16_bf16(kf, qf[kc], s2[tt], 0, 0, 0);
        }
      __builtin_amdgcn_s_setprio(0);

      // causal mask (only tiles overlapping this wave's diagonal)
      const int kv0 = jt * 64;
      if (kv0 + 63 > q0 + w * 32) {
        const int thr = qrow - kv0 - 4 * hi;
#pragma unroll
        for (int tt = 0; tt < 2; tt++)
#pragma unroll
          for (int i = 0; i < 16; i++) {
            const int kvoff = tt * 32 + (i & 3) + 8 * (i >> 2);
            s2[tt][i] = (kvoff > thr) ? -1e30f : s2[tt][i];
          }
      }

      // row max: in-lane tree (max3-friendly nesting) + cross-half shfl
      float mx;
      {
        float m8[8];
#pragma unroll
        for (int i = 0; i < 8; i++)
          m8[i] = fmaxf(fmaxf(s2[0][i], s2[0][i + 8]), fmaxf(s2[1][i], s2[1][i + 8]));
        const float a3 = fmaxf(fmaxf(m8[0], m8[1]), m8[2]);
        const float b3 = fmaxf(fmaxf(m8[3], m8[4]), m8[5]);
        const float c3 = fmaxf(m8[6], m8[7]);
        mx = fmaxf(fmaxf(a3, b3), c3);
      }
      mx = fmaxf(mx, __shfl_xor(mx, 32));

      // defer-max: only rescale when some row's max grew by >8 (2^8 P-bound)
      if (__any(mx > m_run + 8.0f)) {
        const float mnew = fmaxf(m_run, mx);
        const float corr = __builtin_amdgcn_exp2f(m_run - mnew);
        m_run = mnew;
        l_run *= corr;
#pragma unroll
        for (int od = 0; od < 2; od++)
#pragma unroll
          for (int i = 0; i < 16; i++) oacc[od][i] *= corr;
      }

      // p = exp2(s - m)   (logits pre-scaled by log2e at the Q projection)
#pragma unroll
      for (int tt = 0; tt < 2; tt++)
#pragma unroll
        for (int i = 0; i < 16; i++)
          s2[tt][i] = __builtin_amdgcn_exp2f(s2[tt][i] - m_run);

      // row sum: in-lane tree + cross-half shfl
      float rs;
      {
        float a8[8];
#pragma unroll
        for (int i = 0; i < 8; i++)
          a8[i] = (s2[0][i] + s2[0][i + 8]) + (s2[1][i] + s2[1][i + 8]);
#pragma unroll
        for (int st = 4; st > 0; st >>= 1)
#pragma unroll
          for (int i = 0; i < st; i++) a8[i] += a8[i + st];
        rs = a8[0];
      }
      rs += __shfl_xor(rs, 32);
      l_run += rs;

      // build P B-operand fragments: pa[ks] holds kv = ks*16 + hi*8 + j
      union U8 { uint4 u; bf16x8 v; } pa[4];
#pragma unroll
      for (int ks = 0; ks < 4; ks++) {
        const int tt = ks >> 1, b0 = (ks & 1) * 8;
        const unsigned int w0 = pack2(s2[tt][b0 + 0], s2[tt][b0 + 1]);
        const unsigned int w1 = pack2(s2[tt][b0 + 2], s2[tt][b0 + 3]);
        const unsigned int w2 = pack2(s2[tt][b0 + 4], s2[tt][b0 + 5]);
        const unsigned int w3 = pack2(s2[tt][b0 + 6], s2[tt][b0 + 7]);
        const unsigned int p0 = (unsigned int)__shfl_xor((int)w0, 32);
        const unsigned int p1 = (unsigned int)__shfl_xor((int)w1, 32);
        const unsigned int p2 = (unsigned int)__shfl_xor((int)w2, 32);
        const unsigned int p3 = (unsigned int)__shfl_xor((int)w3, 32);
        pa[ks].u = hi ? make_uint4(p2, p3, w2, w3) : make_uint4(w0, w1, p0, p1);
      }

      // O^T += VT * P : D[dh][q]
      __builtin_amdgcn_s_setprio(1);
#pragma unroll
      for (int od = 0; od < 2; od++)
#pragma unroll
        for (int ks = 0; ks < 4; ks++) {
          bf16x8 vf = *(const bf16x8*)&VTs[cur][od * 32 + lo5][ks * 16 + hi * 8];
          oacc[od] = __builtin_amdgcn_mfma_f32_32x32x16_bf16(vf, pa[ks].v, oacc[od], 0, 0, 0);
        }
      __builtin_amdgcn_s_setprio(0);
    }

    // stage next tile into the other buffer (visible after next barrier)
    if (jt + 1 < ntiles) {
      *(uint4*)&Ks[cur ^ 1][rA][kA] = kr0;
      *(uint4*)&Ks[cur ^ 1][rB][kA] = kr1;
      *(uint4*)&VTs[cur ^ 1][rA][kA] = vr0;
      *(uint4*)&VTs[cur ^ 1][rB][kA] = vr1;
    }
  }

  // epilogue: O[b][l][h*64+dh] bf16; lane's q = qrow, dh = crow+od*32
  const float linv = 1.f / l_run;
  unsigned short* Ob = O + ((size_t)(b * LL + qrow) * DM) + h * DH;
#pragma unroll
  for (int od = 0; od < 2; od++)
#pragma unroll
    for (int m = 0; m < 8; m++) {
      const int dh0 = od * 32 + ((2 * m) & 3) + 8 * ((2 * m) >> 2) + 4 * hi;
      const unsigned int pk =
          pack2(oacc[od][2 * m] * linv, oacc[od][2 * m + 1] * linv);
      *(unsigned int*)(Ob + dh0) = pk;
    }
}

// ---------------------------------------------------------------------------
extern "C" void kernel_launch(void* const* d_in, const int* in_sizes, int n_in,
                              void* d_out, int out_size, void* d_ws, size_t ws_size,
                              hipStream_t stream) {
  (void)in_sizes; (void)n_in; (void)out_size;
  const float* q  = (const float*)d_in[0];
  const float* k  = (const float*)d_in[1];
  const float* v  = (const float*)d_in[2];
  const float* Wq = (const float*)d_in[3];
  const float* bq = (const float*)d_in[4];
  const float* Wk = (const float*)d_in[5];
  const float* bk = (const float*)d_in[6];
  const float* Wv = (const float*)d_in[7];
  const float* bv = (const float*)d_in[8];
  const float* Wo = (const float*)d_in[9];
  const float* bo = (const float*)d_in[10];

  char* ws = (char*)d_ws;
  const size_t WSZ = (size_t)DM * DM * 2;     // 2 MB per transposed weight
  const size_t HSZ = (size_t)MROWS * DM * 2;  // 16 MB per bf16 activation
  unsigned short* WT0 = (unsigned short*)(ws);             // WqT,WkT,WvT,WoT contiguous
  unsigned short* WoT = (unsigned short*)(ws + 3 * WSZ);
  unsigned short* Qh  = (unsigned short*)(ws + 4 * WSZ);   // Qh,Kh,VhT contiguous
  unsigned short* Kh  = (unsigned short*)(ws + 4 * WSZ + HSZ);
  unsigned short* VhT = (unsigned short*)(ws + 4 * WSZ + 2 * HSZ);
  unsigned short* X   = (unsigned short*)(ws + 4 * WSZ + 3 * HSZ);  // scratch, later Oc
  unsigned short* Oc  = X;  // X's contents dead once V-GEMM finishes

  const dim3 cgrid(MROWS * DM / (256 * 8));
  const dim3 ggrid(DM / 128, MROWS / 128);
  const size_t NEED = 4 * WSZ + 6 * HSZ;  // 3 extra X buffers

  if (ws_size >= NEED) {
    // merged path: one prep launch (cvt q/k/v + 4 weight transposes),
    // then one z=3 QKV-GEMM launch
    unsigned short* Xq = X;
    unsigned short* Xk = X + (size_t)MROWS * DM;
    unsigned short* Xv = X + 2 * (size_t)MROWS * DM;
    prep_kernel<<<dim3(16384), 256, 0, stream>>>(
        q, k, v, Xq, Xk, Xv, Wq, Wk, Wv, Wo,
        WT0, WT0 + DM * DM, WT0 + 2 * (size_t)DM * DM, WoT);
    qkv_gemm_kernel<<<dim3(DM / 128, MROWS / 128, 3), 256, 0, stream>>>(
        Xq, (size_t)MROWS * DM, WT0, bq, bk, bv, Qh, 0);
  } else {
    // serial path: shared 16MB scratch
    transpose_w_kernel<<<dim3(32, 32, 4), 256, 0, stream>>>(
        Wq, Wk, Wv, Wo,
        WT0, WT0 + DM * DM, WT0 + 2 * (size_t)DM * DM, WoT);
    cvt_bf16_kernel<<<cgrid, 256, 0, stream>>>(q, X);
    qkv_gemm_kernel<<<ggrid, 256, 0, stream>>>(X, 0, WT0, bq, bk, bv, Qh, 0);
    cvt_bf16_kernel<<<cgrid, 256, 0, stream>>>(k, X);
    qkv_gemm_kernel<<<ggrid, 256, 0, stream>>>(X, 0, WT0, bq, bk, bv, Qh, 1);
    cvt_bf16_kernel<<<cgrid, 256, 0, stream>>>(v, X);
    qkv_gemm_kernel<<<ggrid, 256, 0, stream>>>(X, 0, WT0, bq, bk, bv, Qh, 2);
  }

  attn_kernel<<<dim3(16, BB * HEADS), 256, 0, stream>>>(Qh, Kh, VhT, Oc);

  oproj_gemm_kernel<<<ggrid, 256, 0, stream>>>(Oc, WoT, bo, (float*)d_out);
}